// Round 6
// baseline (312.294 us; speedup 1.0000x reference)
//
#include <hip/hip_runtime.h>
#include <math.h>

#define BATCH 8
#define CH 512
#define LEN 2048
#define NG 32
#define CPG 16

typedef unsigned short u16;
typedef __bf16 bf16x8 __attribute__((ext_vector_type(8)));
typedef float f32x16 __attribute__((ext_vector_type(16)));

__device__ __forceinline__ u16 f2bf(float f) {
    union { float f; unsigned u; } c; c.f = f;
    unsigned r = c.u + 0x7fffu + ((c.u >> 16) & 1u);   // RNE
    return (u16)(r >> 16);
}
__device__ __forceinline__ float bf2f(u16 h) {
    union { unsigned u; float f; } c; c.u = ((unsigned)h) << 16;
    return c.f;
}
__device__ __forceinline__ void gload16(const u16* g, u16* l) {
    __builtin_amdgcn_global_load_lds(
        (const __attribute__((address_space(1))) unsigned int*)g,
        (__attribute__((address_space(3))) unsigned int*)l, 16, 0, 0);
}

#define BARRIER() do {                                   \
    asm volatile("" ::: "memory");                       \
    __builtin_amdgcn_s_barrier();                        \
    asm volatile("" ::: "memory");                       \
} while (0)

// ---------------------------------------------------------------------------
__global__ __launch_bounds__(256) void zerof4(float4* __restrict__ p) {
    p[blockIdx.x * 256 + threadIdx.x] = make_float4(0.f, 0.f, 0.f, 0.f);
}

// ---------------------------------------------------------------------------
__global__ __launch_bounds__(256) void wconv4(const float* __restrict__ w0, const float* __restrict__ w1,
                                              const float* __restrict__ w2, const float* __restrict__ w3,
                                              u16* __restrict__ o0, u16* __restrict__ o1,
                                              u16* __restrict__ o2, u16* __restrict__ o3) {
    const float* s; u16* d;
    switch (blockIdx.y) {
        case 0: s = w0; d = o0; break;
        case 1: s = w1; d = o1; break;
        case 2: s = w2; d = o2; break;
        default: s = w3; d = o3; break;
    }
    const int i = blockIdx.x * 256 + threadIdx.x;
    float4 f = ((const float4*)s)[i];
    ushort4 o = make_ushort4(f2bf(f.x), f2bf(f.y), f2bf(f.z), f2bf(f.w));
    ((ushort4*)d)[i] = o;
}

// ---------------------------------------------------------------------------
__global__ __launch_bounds__(256) void gn_stats(const float* __restrict__ x,
                                                const float* __restrict__ gw,
                                                const float* __restrict__ gb,
                                                float* __restrict__ gnA,
                                                float* __restrict__ gnB) {
    const int b = blockIdx.x >> 5, g = blockIdx.x & 31;
    const float4* xp = (const float4*)(x + ((size_t)b * CH + (size_t)g * CPG) * LEN);
    float s = 0.f, s2 = 0.f;
    for (int i = threadIdx.x; i < (CPG * LEN) / 4; i += 256) {
        float4 v = xp[i];
        s += v.x + v.y + v.z + v.w;
        s2 = fmaf(v.x, v.x, fmaf(v.y, v.y, fmaf(v.z, v.z, fmaf(v.w, v.w, s2))));
    }
    #pragma unroll
    for (int off = 32; off > 0; off >>= 1) {
        s  += __shfl_down(s, off, 64);
        s2 += __shfl_down(s2, off, 64);
    }
    __shared__ float sm[2][4];
    const int lane = threadIdx.x & 63, wv = threadIdx.x >> 6;
    if (lane == 0) { sm[0][wv] = s; sm[1][wv] = s2; }
    __syncthreads();
    if (threadIdx.x < CPG) {
        const float S  = sm[0][0] + sm[0][1] + sm[0][2] + sm[0][3];
        const float S2 = sm[1][0] + sm[1][1] + sm[1][2] + sm[1][3];
        const float mean = S * (1.f / (CPG * LEN));
        const float var  = S2 * (1.f / (CPG * LEN)) - mean * mean;
        const float rstd = rsqrtf(var + 1e-6f);
        const int c = g * CPG + threadIdx.x;
        const float sc = rstd * gw[c];
        gnA[b * CH + c] = sc;
        gnB[b * CH + c] = gb[c] - mean * sc;
    }
}

// ---------------------------------------------------------------------------
__global__ __launch_bounds__(256) void gn_apply_t(const float* __restrict__ x,
                                                  const float* __restrict__ gnA,
                                                  const float* __restrict__ gnB,
                                                  u16* __restrict__ Ht) {
    __shared__ float tile[64][65];
    const int b = blockIdx.z, c0 = blockIdx.y * 64, l0 = blockIdx.x * 64;
    const int t = threadIdx.x, tl = t & 63, tr = t >> 6;
    #pragma unroll 4
    for (int i = 0; i < 16; ++i) {
        const int c = tr + i * 4;
        const float a = gnA[b * CH + c0 + c];
        const float sh = gnB[b * CH + c0 + c];
        tile[c][tl] = x[((size_t)b * CH + c0 + c) * LEN + l0 + tl] * a + sh;
    }
    __syncthreads();
    #pragma unroll 4
    for (int i = 0; i < 16; ++i) {
        const int l = tr + i * 4;
        Ht[((size_t)b * LEN + l0 + l) * CH + c0 + tl] = f2bf(tile[tl][l]);
    }
}

#define EPI_QK   0
#define EPI_TBN  1
#define EPI_EXP  2
#define EPI_TNRM 3
#define EPI_FIN  4

// ---------------------------------------------------------------------------
// 8-phase-class MFMA GEMM, 256x256 tile, BK=64, 2-buffer LDS (128 KB),
// 512 threads = 8 waves (2M x 4N), wave tile 128x64, mfma_f32_32x32x16_bf16,
// acc[4][2] f32x16. Per K-tile: 4 quadrant phases, each
//   { 12 ds_read_b128 ; 2 global_load_lds (next tile, deadline-ordered) ;
//     [wait] ; barrier ; setprio(1) ; 8 MFMA ; setprio(0) ; barrier }
// Counted vmcnt NEVER drains to 0 in steady state:
//   - stage order for tile t+1 (during tile t): B0,B1 | B2,B3 | A0,A2 | A1,A3
//     (B units + A-even have phase-0 deadlines; A-odd (rows 64-127/192-255)
//     are first read in phase 1 -> may lag).
//   - phase-3 tail: vmcnt(2) before the end barrier -> waits B0-3,A0,A2 of
//     t+1 (issued >=1.5 phases earlier), leaves A1,A3 in flight.
//   - phase-0: vmcnt(2) before the pre-MFMA barrier -> drains A1,A3 of the
//     CURRENT tile (issued 2 phases earlier); the barrier publishes them for
//     phase-1 reads. (Per-wave wait + subsequent barrier = cross-wave safe.)
// Unit = 64 rows x 128 B = 512 thr x 16 B (one gload/thread). XOR swizzle
// identical to gemm_bt: slot s of row r holds global chunk s^(r&7).
// ---------------------------------------------------------------------------
template <int MODE>
__global__ __launch_bounds__(512, 2) void gemm8p(
    const u16* __restrict__ A, int lda, long long sA,
    const u16* __restrict__ B, int ldb, long long sB,
    void* __restrict__ Out, void* __restrict__ Out2,
    int ldo, long long sO,
    const float* __restrict__ bias, const float* __restrict__ bias2,
    float* __restrict__ rsum, long long sRS,
    int K, float alpha) {
    __shared__ u16 As[2][256 * 64];   // 64 KB
    __shared__ u16 Bs[2][256 * 64];   // 64 KB

    // bijective XCD remap (all grids % 8 == 0)
    const int gx = gridDim.x, gy = gridDim.y;
    int flat = (blockIdx.z * gy + blockIdx.y) * gx + blockIdx.x;
    const int nbk = gx * gy * (int)gridDim.z;
    flat = (flat & 7) * (nbk >> 3) + (flat >> 3);
    const int bz = flat / (gx * gy);
    const int rr = flat - bz * gx * gy;
    const int by = rr / gx;
    const int bx = rr - by * gx;

    const int n0 = bx * 256, m0 = by * 256;
    A += (size_t)bz * sA;
    B += (size_t)bz * sB;

    const int t = threadIdx.x;
    const int lane = t & 63, wid = t >> 6;
    const int col = lane & 31, half = lane >> 5;
    const int wm = (wid >> 2) * 128, wn = (wid & 3) * 64;
    const int cswz = col & 7;

    const int rowL = t >> 3;
    const int kq8 = ((t & 7) ^ (rowL & 7)) * 8;
    unsigned aoff[4], boff[4];
    #pragma unroll
    for (int u = 0; u < 4; ++u) {
        aoff[u] = (unsigned)((m0 + u * 64 + rowL) * lda + kq8);
        boff[u] = (unsigned)((n0 + u * 64 + rowL) * ldb + kq8);
    }
    const int dst = t * 8;   // u16 offset inside a 4096-u16 unit

    f32x16 acc[4][2];
    #pragma unroll
    for (int mi = 0; mi < 4; ++mi)
        #pragma unroll
        for (int nj = 0; nj < 2; ++nj)
            acc[mi][nj] = (f32x16)(0.f);

    auto stA = [&](int u, unsigned ko, u16* buf) { gload16(A + aoff[u] + ko, buf + u * 4096 + dst); };
    auto stB = [&](int u, unsigned ko, u16* buf) { gload16(B + boff[u] + ko, buf + u * 4096 + dst); };

#define PHASE(QM, QN, STG, W1, W2) do {                                             \
    bf16x8 av0[4], av1[4], bv[4];                                                   \
    _Pragma("unroll")                                                               \
    for (int ks = 0; ks < 4; ++ks) {                                                \
        const int sl = ((ks * 2 + half) ^ cswz) * 8;                                \
        av0[ks] = *(const bf16x8*)(Ac + (wm + (QM) * 64      + col) * 64 + sl);     \
        av1[ks] = *(const bf16x8*)(Ac + (wm + (QM) * 64 + 32 + col) * 64 + sl);     \
        bv[ks]  = *(const bf16x8*)(Bc + (wn + (QN) * 32 + col) * 64 + sl);          \
    }                                                                               \
    STG; W1;                                                                        \
    BARRIER();                                                                      \
    __builtin_amdgcn_s_setprio(1);                                                  \
    _Pragma("unroll")                                                               \
    for (int ks = 0; ks < 4; ++ks) {                                                \
        acc[(QM)*2+0][QN] = __builtin_amdgcn_mfma_f32_32x32x16_bf16(av0[ks], bv[ks], acc[(QM)*2+0][QN], 0, 0, 0); \
        acc[(QM)*2+1][QN] = __builtin_amdgcn_mfma_f32_32x32x16_bf16(av1[ks], bv[ks], acc[(QM)*2+1][QN], 0, 0, 0); \
    }                                                                               \
    __builtin_amdgcn_s_setprio(0);                                                  \
    W2;                                                                             \
    BARRIER();                                                                      \
} while (0)

    // prologue: tile 0, deadline order; last-issued = A1,A3
    stB(0, 0, Bs[0]); stB(1, 0, Bs[0]); stB(2, 0, Bs[0]); stB(3, 0, Bs[0]);
    stA(0, 0, As[0]); stA(2, 0, As[0]); stA(1, 0, As[0]); stA(3, 0, As[0]);
    asm volatile("s_waitcnt vmcnt(2)" ::: "memory");
    BARRIER();

    const int NT = K >> 6;
    for (int kt = 0; kt < NT; ++kt) {
        const u16* Ac = As[kt & 1];
        const u16* Bc = Bs[kt & 1];
        u16* An = As[(kt + 1) & 1];
        u16* Bn = Bs[(kt + 1) & 1];
        const bool pf = (kt + 1 < NT);
        const unsigned ko = (unsigned)((kt + 1) << 6);

        PHASE(0, 0,
              if (pf) { stB(0, ko, Bn); stB(1, ko, Bn); },
              if (pf) { asm volatile("s_waitcnt vmcnt(2)" ::: "memory"); }
              else    { asm volatile("s_waitcnt vmcnt(0)" ::: "memory"); }, );
        PHASE(1, 0,
              if (pf) { stB(2, ko, Bn); stB(3, ko, Bn); }, , );
        PHASE(0, 1,
              if (pf) { stA(0, ko, An); stA(2, ko, An); }, , );
        PHASE(1, 1,
              if (pf) { stA(1, ko, An); stA(3, ko, An); }, ,
              if (pf) { asm volatile("s_waitcnt vmcnt(2)" ::: "memory"); });
    }
#undef PHASE

    // C/D: col = lane&31 (n), row = (reg&3) + 8*(reg>>2) + 4*half (+ 32*mi)
    if (MODE == EPI_EXP) {
        u16* O = (u16*)Out + (size_t)bz * sO;
        float* RS = rsum + (size_t)bz * sRS;
        float psum[2] = {0.f, 0.f};
        #pragma unroll
        for (int im = 0; im < 4; ++im)
            #pragma unroll
            for (int g4 = 0; g4 < 4; ++g4) {
                const int mb = m0 + wm + im * 32 + g4 * 8 + half * 4;
                #pragma unroll
                for (int jn = 0; jn < 2; ++jn) {
                    const int n = n0 + wn + jn * 32 + col;
                    u16 h0 = f2bf(__expf(acc[im][jn][g4 * 4 + 0] * alpha));
                    u16 h1 = f2bf(__expf(acc[im][jn][g4 * 4 + 1] * alpha));
                    u16 h2 = f2bf(__expf(acc[im][jn][g4 * 4 + 2] * alpha));
                    u16 h3 = f2bf(__expf(acc[im][jn][g4 * 4 + 3] * alpha));
                    psum[jn] += bf2f(h0) + bf2f(h1) + bf2f(h2) + bf2f(h3);
                    *(ushort4*)&O[(size_t)n * ldo + mb] = make_ushort4(h0, h1, h2, h3);
                }
            }
        #pragma unroll
        for (int jn = 0; jn < 2; ++jn) psum[jn] += __shfl_xor(psum[jn], 32, 64);
        if (half == 0) {
            #pragma unroll
            for (int jn = 0; jn < 2; ++jn)
                atomicAdd(&RS[n0 + wn + jn * 32 + col], psum[jn]);
        }
    } else {   // EPI_QK
        const bool hi = (m0 & 512) != 0;
        u16* O = (u16*)(hi ? Out2 : Out) + (size_t)bz * sO;
        const float* bi = hi ? bias2 : bias;
        const int mbase = (m0 & 511) + wm;
        #pragma unroll
        for (int im = 0; im < 4; ++im)
            #pragma unroll
            for (int g4 = 0; g4 < 4; ++g4) {
                const int mb = mbase + im * 32 + g4 * 8 + half * 4;
                const float4 bm = *(const float4*)&bi[mb];
                #pragma unroll
                for (int jn = 0; jn < 2; ++jn) {
                    const int n = n0 + wn + jn * 32 + col;
                    ushort4 pk = make_ushort4(f2bf(acc[im][jn][g4 * 4 + 0] + bm.x),
                                              f2bf(acc[im][jn][g4 * 4 + 1] + bm.y),
                                              f2bf(acc[im][jn][g4 * 4 + 2] + bm.z),
                                              f2bf(acc[im][jn][g4 * 4 + 3] + bm.w));
                    *(ushort4*)&O[(size_t)n * ldo + mb] = pk;
                }
            }
    }
}

// ---------------------------------------------------------------------------
// r4 128x128 kernel (proven) for V / PV / final
// ---------------------------------------------------------------------------
template <int MODE>
__global__ __launch_bounds__(256, 4) void gemm_bt(
    const u16* __restrict__ A, int lda, long long sA,
    const u16* __restrict__ B, int ldb, long long sB,
    void* __restrict__ Out, void* __restrict__ Out2,
    int ldo, long long sO,
    const float* __restrict__ bias, const float* __restrict__ bias2,
    const float* __restrict__ res, long long sR,
    float* __restrict__ rsum, long long sRS,
    int K, float alpha) {
    __shared__ u16 As[128 * 64];
    __shared__ u16 Bs[128 * 64];
    const int b = blockIdx.z;
    const int n0 = blockIdx.x * 128, m0 = blockIdx.y * 128;
    A += (size_t)b * sA;
    B += (size_t)b * sB;
    const int t = threadIdx.x;
    const int lane = t & 63, wid = t >> 6;

    const int rowL = t >> 3, kq = (t & 7) ^ (rowL & 7);
    unsigned aoff = (unsigned)((m0 + rowL) * lda + kq * 8);
    unsigned boff = (unsigned)((n0 + rowL) * ldb + kq * 8);
    u16* const lds_dst_a = As + t * 8;
    u16* const lds_dst_b = Bs + t * 8;

    f32x16 acc[2][2];
    #pragma unroll
    for (int i = 0; i < 2; ++i)
        #pragma unroll
        for (int j = 0; j < 2; ++j)
            acc[i][j] = (f32x16)(0.f);

    const int col = lane & 31, half = lane >> 5;
    const int wm = (wid & 1) * 64, wn = (wid >> 1) * 64;
    const int mf = wm + col, nf = wn + col;
    const int mswz = mf & 7, nswz = nf & 7;

    for (int k0 = 0; k0 < K; k0 += 64) {
        #pragma unroll
        for (int g = 0; g < 4; ++g) {
            gload16(A + aoff + g * (32 * lda), lds_dst_a + g * 2048);
            gload16(B + boff + g * (32 * ldb), lds_dst_b + g * 2048);
        }
        aoff += 64; boff += 64;
        __syncthreads();
        #pragma unroll
        for (int ks = 0; ks < 4; ++ks) {
            const int kcA = ((ks * 2 + half) ^ mswz) * 8;
            const int kcB = ((ks * 2 + half) ^ nswz) * 8;
            bf16x8 a0 = *(const bf16x8*)(As + (mf)      * 64 + kcA);
            bf16x8 a1 = *(const bf16x8*)(As + (mf + 32) * 64 + kcA);
            bf16x8 b0 = *(const bf16x8*)(Bs + (nf)      * 64 + kcB);
            bf16x8 b1 = *(const bf16x8*)(Bs + (nf + 32) * 64 + kcB);
            acc[0][0] = __builtin_amdgcn_mfma_f32_32x32x16_bf16(a0, b0, acc[0][0], 0, 0, 0);
            acc[0][1] = __builtin_amdgcn_mfma_f32_32x32x16_bf16(a0, b1, acc[0][1], 0, 0, 0);
            acc[1][0] = __builtin_amdgcn_mfma_f32_32x32x16_bf16(a1, b0, acc[1][0], 0, 0, 0);
            acc[1][1] = __builtin_amdgcn_mfma_f32_32x32x16_bf16(a1, b1, acc[1][1], 0, 0, 0);
        }
        __syncthreads();
    }

    if (MODE == EPI_FIN) {
        float* O = (float*)Out + (size_t)b * sO;
        const float* R = res + (size_t)b * sR;
        #pragma unroll
        for (int im = 0; im < 2; ++im)
            #pragma unroll
            for (int g4 = 0; g4 < 4; ++g4) {
                const int mb = m0 + wm + im * 32 + g4 * 8 + half * 4;
                #pragma unroll
                for (int jn = 0; jn < 2; ++jn) {
                    const int n = n0 + wn + jn * 32 + col;
                    const float bb = bias[n];
                    const size_t base = (size_t)n * ldo + mb;
                    const float4 r4 = *(const float4*)&R[base];
                    float4 o4;
                    o4.x = acc[im][jn][g4 * 4 + 0] + bb + r4.x;
                    o4.y = acc[im][jn][g4 * 4 + 1] + bb + r4.y;
                    o4.z = acc[im][jn][g4 * 4 + 2] + bb + r4.z;
                    o4.w = acc[im][jn][g4 * 4 + 3] + bb + r4.w;
                    *(float4*)&O[base] = o4;
                }
            }
    } else {
        u16* O = (u16*)Out + (size_t)b * sO;
        const float* bi = bias;
        const float* RS = (MODE == EPI_TNRM) ? rsum + (size_t)b * sRS : nullptr;
        const int mbase = m0 + wm;
        float inv[2];
        if (MODE == EPI_TNRM) {
            inv[0] = 1.f / RS[n0 + wn + col];
            inv[1] = 1.f / RS[n0 + wn + 32 + col];
        }
        #pragma unroll
        for (int im = 0; im < 2; ++im)
            #pragma unroll
            for (int g4 = 0; g4 < 4; ++g4) {
                const int mb = mbase + im * 32 + g4 * 8 + half * 4;
                #pragma unroll
                for (int jn = 0; jn < 2; ++jn) {
                    const int n = n0 + wn + jn * 32 + col;
                    float v0 = acc[im][jn][g4 * 4 + 0];
                    float v1 = acc[im][jn][g4 * 4 + 1];
                    float v2 = acc[im][jn][g4 * 4 + 2];
                    float v3 = acc[im][jn][g4 * 4 + 3];
                    if (MODE == EPI_TBN) { const float bb = bi[n]; v0 += bb; v1 += bb; v2 += bb; v3 += bb; }
                    if (MODE == EPI_TNRM) { v0 *= inv[jn]; v1 *= inv[jn]; v2 *= inv[jn]; v3 *= inv[jn]; }
                    ushort4 pk = make_ushort4(f2bf(v0), f2bf(v1), f2bf(v2), f2bf(v3));
                    *(ushort4*)&O[(size_t)n * ldo + mb] = pk;
                }
            }
    }
}

// ---------------------------------------------------------------------------
extern "C" void kernel_launch(void* const* d_in, const int* in_sizes, int n_in,
                              void* d_out, int out_size, void* d_ws, size_t ws_size,
                              hipStream_t stream) {
    const float* x    = (const float*)d_in[0];
    const float* gn_w = (const float*)d_in[1];
    const float* gn_b = (const float*)d_in[2];
    const float* wq   = (const float*)d_in[3];
    const float* bq   = (const float*)d_in[4];
    const float* wk   = (const float*)d_in[5];
    const float* bk   = (const float*)d_in[6];
    const float* wv   = (const float*)d_in[7];
    const float* bv   = (const float*)d_in[8];
    const float* wo   = (const float*)d_in[9];
    const float* bo   = (const float*)d_in[10];
    float* out = (float*)d_out;

    char* p = (char*)d_ws;
    const size_t WSZ = (size_t)CH * CH * 2;
    const size_t HSZ = (size_t)BATCH * CH * LEN * 2;
    u16* Wqk = (u16*)p; p += 2 * WSZ;   // rows 0-511 = Wq, 512-1023 = Wk
    u16* Wvb = (u16*)p; p += WSZ;
    u16* Wob = (u16*)p; p += WSZ;
    u16* Ht  = (u16*)p; p += HSZ;   // GN out [b][l][c]; later PV out [b][i][c]
    u16* Qt  = (u16*)p; p += HSZ;   // [b][l][c]
    u16* Kt  = (u16*)p; p += HSZ;   // [b][l][c]
    u16* Vb  = (u16*)p; p += HSZ;   // [b][c][l]
    u16* Sb  = (u16*)p; p += (size_t)BATCH * LEN * LEN * 2;  // exp(scores)
    float* gnA = (float*)p; p += (size_t)BATCH * CH * 4;
    float* gnB = (float*)p; p += (size_t)BATCH * CH * 4;
    float* rowsum = (float*)p;      // BATCH * LEN fp32

    const long long sH = (long long)LEN * CH;
    const long long sV = (long long)CH * LEN;
    const long long sS = (long long)LEN * LEN;
    const float scale = 0.04419417382415922f;   // 512^-0.5

    wconv4<<<dim3(256, 4), 256, 0, stream>>>(wq, wk, wv, wo,
                                             Wqk, Wqk + (size_t)CH * CH, Wvb, Wob);
    gn_stats<<<BATCH * NG, 256, 0, stream>>>(x, gn_w, gn_b, gnA, gnB);
    gn_apply_t<<<dim3(LEN / 64, CH / 64, BATCH), 256, 0, stream>>>(x, gnA, gnB, Ht);
    zerof4<<<BATCH * LEN / 1024, 256, 0, stream>>>((float4*)rowsum);

    // Q+K fused (8-phase 256^2): A=Wqk (m=o, M=1024), B=Ht (n=l) -> Qt/Kt[l][o]
    gemm8p<EPI_QK><<<dim3(8, 4, 8), 512, 0, stream>>>(
        Wqk, CH, 0, Ht, CH, sH, Qt, Kt, CH, sH, bq, bk, nullptr, 0, CH, 0.f);
    // V: A=Ht (m=l), B=Wv (n=c) -> Vb[c][l], bias[c]
    gemm_bt<EPI_TBN><<<dim3(4, 16, 8), 256, 0, stream>>>(
        Ht, CH, sH, Wvb, CH, 0, Vb, nullptr, LEN, sV, bv, nullptr, nullptr, 0, nullptr, 0, CH, 0.f);
    // scores (8-phase 256^2): A=Kt (m=j), B=Qt (n=i) -> E[i][j]=exp(scale*S), rowsum[i]
    gemm8p<EPI_EXP><<<dim3(8, 8, 8), 512, 0, stream>>>(
        Kt, CH, sH, Qt, CH, sH, Sb, nullptr, LEN, sS, nullptr, nullptr, rowsum, LEN, CH, scale);
    // PV: A=Vb (m=c), B=E (n=i) -> Ht[i][c], * 1/rowsum[i]
    gemm_bt<EPI_TNRM><<<dim3(16, 4, 8), 256, 0, stream>>>(
        Vb, LEN, sV, Sb, LEN, sS, Ht, nullptr, CH, sH, nullptr, nullptr, nullptr, 0, rowsum, LEN, LEN, 0.f);
    // final: A=Ht (m=l), B=Wo (n=o) -> out[o][l] f32 + bias[o] + x residual
    gemm_bt<EPI_FIN><<<dim3(4, 16, 8), 256, 0, stream>>>(
        Ht, CH, sH, Wob, CH, 0, out, nullptr, LEN, sV, bo, nullptr, x, sV, nullptr, 0, CH, 0.f);
}